// Round 6
// baseline (381.224 us; speedup 1.0000x reference)
//
#include <hip/hip_runtime.h>
#include <math.h>

// Problem constants (from reference)
#define NPTS   65536        // 256*256
#define NB     5
#define NX     25
#define NY     7
#define NZ     6
#define NW     5
#define FG     (NB*NX*NY*NZ*NW)       // 26250 f_grid elements
#define GRID_ELEMS (2000 * FG)        // 52,500,000
// out layout: [0]=loss, [1 .. 65536]=theta[0], [65537 ..]=grid_new
// ws layout: [0..4]=s[n], [5]=sum|theta|, [6]=sum(f*W4)
//
// dst base (out+65537 floats) is 4 mod 16 bytes. Copy strategy: dst chunks
// start at element 3+4m (16B-aligned on dst). Each chunk is assembled from
// TWO 16B-ALIGNED src loads (elements [4m..4m+3] and [4m+4..4m+7]):
//   v = {a.w, b.x, b.y, b.z}
// The overlapping 2nd load hits lines the neighbor lane fetched -> L1 dedup.
// => x4 width on both sides, zero split transactions, 3 VMEM instr / 16B.

#define NCHUNKM ((GRID_ELEMS - 4) / 4)   // 13,124,999 chunks; last chunk's
                                         // b-load ends at GRID_ELEMS-1 (in bounds)
#define COPY_TPB  256
#define COPY_CPT  4                      // chunks per thread
#define COPY_TILE (COPY_TPB * COPY_CPT)  // 1024 chunks per block

typedef float float4v __attribute__((ext_vector_type(4), aligned(16)));

__device__ __forceinline__ float fgrid_eval(const float* s, int e2, float* w4out) {
    const float PI2 = 6.283185307179586f;
    const float dxs = PI2 / 24.0f;
    const float dys = 0.03f;          // 0.18/6
    const float dzs = 0.036f;         // 0.18/5
    const float dws = 0.05f;          // 0.2/4
    int d  = e2 % NW;
    int cz = (e2 / NW) % NZ;
    int b  = (e2 / (NW * NZ)) % NY;
    int a  = (e2 / (NW * NZ * NY)) % NX;
    int n  = e2 / (NW * NZ * NY * NX);
    float xv = PI2 * (float)a / 24.0f;
    float cv = cosf(xv);
    float yv = -0.09f + dys * (float)b;
    float zv = -0.09f + dzs * (float)cz;
    float wv = 0.9f  + dws * (float)d;
    float arg = s[n] * cv * wv + yv + zv;
    float f = expf(-arg * arg);
    *w4out = dxs * ((a == 0 || a == NX - 1) ? 0.5f : 1.0f)
           * dys * ((b == 0 || b == NY - 1) ? 0.5f : 1.0f)
           * dzs * ((cz == 0 || cz == NZ - 1) ? 0.5f : 1.0f)
           * dws * ((d == 0 || d == NW - 1) ? 0.5f : 1.0f);
    return f;
}

// Kernel A: s[n] = sum_i x[n,i]*theta[i], ws[5] = sum|theta|, theta passthrough.
__global__ void reduce_kernel(const float* __restrict__ x,
                              const float* __restrict__ theta,
                              float* __restrict__ out_theta,
                              float* __restrict__ ws) {
    __shared__ float smem[4 * 6];
    int idx = blockIdx.x * blockDim.x + threadIdx.x;   // 0..65535
    float t = theta[idx];
    out_theta[idx] = t;

    float vals[6];
#pragma unroll
    for (int n = 0; n < 5; ++n) vals[n] = x[n * NPTS + idx] * t;
    vals[5] = fabsf(t);

    int lane = threadIdx.x & 63;
    int wave = threadIdx.x >> 6;
#pragma unroll
    for (int k = 0; k < 6; ++k) {
        float v = vals[k];
#pragma unroll
        for (int off = 32; off > 0; off >>= 1) v += __shfl_down(v, off, 64);
        if (lane == 0) smem[wave * 6 + k] = v;
    }
    __syncthreads();
    if (threadIdx.x < 6) {
        float acc = smem[threadIdx.x] + smem[6 + threadIdx.x] +
                    smem[12 + threadIdx.x] + smem[18 + threadIdx.x];
        atomicAdd(&ws[threadIdx.x], acc);
    }
}

// Kernel B: copy with both sides 16B-aligned (register shift, see header).
// Thread handles chunks {base + k*256}: every sub-pass fully coalesced.
__global__ void __launch_bounds__(COPY_TPB)
copy_kernel(const float* __restrict__ src,
            float* __restrict__ dst) {          // dst = out + 1 + NPTS
    const int base = blockIdx.x * COPY_TILE + threadIdx.x;
#pragma unroll
    for (int k = 0; k < COPY_CPT; ++k) {
        const int m = base + k * COPY_TPB;
        if (m < NCHUNKM) {
            const float4v a = *(const float4v*)(src + 4 * m);      // aligned
            const float4v b = *(const float4v*)(src + 4 * m + 4);  // aligned, L1-hot
            float4v v = {a[3], b[0], b[1], b[2]};
            __builtin_nontemporal_store(v, (float4v*)(dst + 3 + 4 * m));
        }
    }
    if (blockIdx.x == 0 && threadIdx.x == 0) {   // edge elements
        dst[0] = src[0];
        dst[1] = src[1];
        dst[2] = src[2];
        dst[GRID_ELEMS - 1] = src[GRID_ELEMS - 1];
    }
}

// Kernel C: overwrite slot j with f_grid (26250 elems) + loss partial sum.
__global__ void __launch_bounds__(256)
fgrid_kernel(const float* __restrict__ ws_in,
             float* __restrict__ ws_out,
             const int* __restrict__ jptr,
             float* __restrict__ out_grid) {    // out + 1 + NPTS
    __shared__ float smem[4];
    const int e = blockIdx.x * 256 + threadIdx.x;

    float s[5];
#pragma unroll
    for (int n = 0; n < 5; ++n) s[n] = ws_in[n];
    const int j = *jptr;

    float local = 0.0f;
    if (e < FG) {
        float w4;
        float f = fgrid_eval(s, e, &w4);
        out_grid[j * FG + e] = f;
        local = f * w4;
    }
#pragma unroll
    for (int off = 32; off > 0; off >>= 1) local += __shfl_down(local, off, 64);
    int lane = threadIdx.x & 63, wave = threadIdx.x >> 6;
    if (lane == 0) smem[wave] = local;
    __syncthreads();
    if (threadIdx.x == 0)
        atomicAdd(&ws_out[6], smem[0] + smem[1] + smem[2] + smem[3]);
}

// Kernel D: finalize loss
__global__ void finalize_kernel(const float* __restrict__ ws,
                                float* __restrict__ out) {
    out[0] = ws[6] - 0.5f * ws[5];
}

extern "C" void kernel_launch(void* const* d_in, const int* in_sizes, int n_in,
                              void* d_out, int out_size, void* d_ws, size_t ws_size,
                              hipStream_t stream) {
    const float* x     = (const float*)d_in[0];   // [5,256,256]
    const float* theta = (const float*)d_in[1];   // [1,256,256]
    const float* grid  = (const float*)d_in[2];   // [2000,5,25,7,6,5]
    const int*   jptr  = (const int*)d_in[3];     // scalar

    float* out = (float*)d_out;
    float* ws  = (float*)d_ws;

    hipMemsetAsync(ws, 0, 7 * sizeof(float), stream);

    reduce_kernel<<<NPTS / 256, 256, 0, stream>>>(x, theta, out + 1, ws);

    const int nblk = (NCHUNKM + COPY_TILE - 1) / COPY_TILE;   // 12818
    copy_kernel<<<nblk, COPY_TPB, 0, stream>>>(grid, out + 1 + NPTS);

    fgrid_kernel<<<(FG + 255) / 256, 256, 0, stream>>>(ws, ws, jptr,
                                                       out + 1 + NPTS);

    finalize_kernel<<<1, 1, 0, stream>>>(ws, out);
}

// Round 7
// 379.852 us; speedup vs baseline: 1.0036x; 1.0036x over previous
//
#include <hip/hip_runtime.h>
#include <math.h>

// Problem constants (from reference)
#define NPTS   65536        // 256*256
#define NB     5
#define NX     25
#define NY     7
#define NZ     6
#define NW     5
#define FG     (NB*NX*NY*NZ*NW)       // 26250 f_grid elements
#define GRID_ELEMS (2000 * FG)        // 52,500,000
// out layout: [0]=loss, [1 .. 65536]=theta[0], [65537 ..]=grid_new
// ws layout: [0..4]=s[n], [5]=sum|theta|, [6]=sum(f*W4)
//
// Copy scheme: dst chunks start at element 3+4m (16B-aligned on dst since the
// dst base is 4 mod 16). Lane l holds chunk m = tile + k*256 + l; its dst
// chunk needs src elements [4m+3 .. 4m+6] = own a[3] + NEXT chunk's a[0..2],
// which lane l+1 already loaded -> 3 x __shfl_down instead of a 2nd load.
// Wave-boundary / last-chunk lanes do one patch load. => ~2.02 VMEM per 16B,
// both sides 16B-aligned. Blocks process tiles in REVERSE so the first-
// dispatched blocks read the most-recently-restored (L3-resident) tail.

#define NCHUNKM ((GRID_ELEMS - 4) / 4)   // 13,124,999 chunks
#define COPY_TPB  256
#define COPY_CPT  4
#define COPY_TILE (COPY_TPB * COPY_CPT)  // 1024 chunks per block

typedef float float4v __attribute__((ext_vector_type(4), aligned(16)));

__device__ __forceinline__ float fgrid_eval(const float* s, int e2, float* w4out) {
    const float PI2 = 6.283185307179586f;
    const float dxs = PI2 / 24.0f;
    const float dys = 0.03f;          // 0.18/6
    const float dzs = 0.036f;         // 0.18/5
    const float dws = 0.05f;          // 0.2/4
    int d  = e2 % NW;
    int cz = (e2 / NW) % NZ;
    int b  = (e2 / (NW * NZ)) % NY;
    int a  = (e2 / (NW * NZ * NY)) % NX;
    int n  = e2 / (NW * NZ * NY * NX);
    float xv = PI2 * (float)a / 24.0f;
    float cv = cosf(xv);
    float yv = -0.09f + dys * (float)b;
    float zv = -0.09f + dzs * (float)cz;
    float wv = 0.9f  + dws * (float)d;
    float arg = s[n] * cv * wv + yv + zv;
    float f = expf(-arg * arg);
    *w4out = dxs * ((a == 0 || a == NX - 1) ? 0.5f : 1.0f)
           * dys * ((b == 0 || b == NY - 1) ? 0.5f : 1.0f)
           * dzs * ((cz == 0 || cz == NZ - 1) ? 0.5f : 1.0f)
           * dws * ((d == 0 || d == NW - 1) ? 0.5f : 1.0f);
    return f;
}

// Kernel A: s[n] = sum_i x[n,i]*theta[i], ws[5] = sum|theta|, theta passthrough.
__global__ void reduce_kernel(const float* __restrict__ x,
                              const float* __restrict__ theta,
                              float* __restrict__ out_theta,
                              float* __restrict__ ws) {
    __shared__ float smem[4 * 6];
    int idx = blockIdx.x * blockDim.x + threadIdx.x;   // 0..65535
    float t = theta[idx];
    out_theta[idx] = t;

    float vals[6];
#pragma unroll
    for (int n = 0; n < 5; ++n) vals[n] = x[n * NPTS + idx] * t;
    vals[5] = fabsf(t);

    int lane = threadIdx.x & 63;
    int wave = threadIdx.x >> 6;
#pragma unroll
    for (int k = 0; k < 6; ++k) {
        float v = vals[k];
#pragma unroll
        for (int off = 32; off > 0; off >>= 1) v += __shfl_down(v, off, 64);
        if (lane == 0) smem[wave * 6 + k] = v;
    }
    __syncthreads();
    if (threadIdx.x < 6) {
        float acc = smem[threadIdx.x] + smem[6 + threadIdx.x] +
                    smem[12 + threadIdx.x] + smem[18 + threadIdx.x];
        atomicAdd(&ws[threadIdx.x], acc);
    }
}

// Kernel B: shuffle-shift copy, reverse tile order (see header comment).
__global__ void __launch_bounds__(COPY_TPB)
copy_kernel(const float* __restrict__ src,
            float* __restrict__ dst) {          // dst = out + 1 + NPTS
    const int tile = ((int)gridDim.x - 1 - (int)blockIdx.x) * COPY_TILE;
    const int lane = (int)threadIdx.x & 63;

#pragma unroll
    for (int k = 0; k < COPY_CPT; ++k) {
        const int m  = tile + k * COPY_TPB + (int)threadIdx.x;
        const int mc = (m < NCHUNKM) ? m : (NCHUNKM - 1);   // clamp: all lanes
                                                            // participate in shfl
        const float4v a = *(const float4v*)(src + 4 * mc);  // 16B-aligned

        // lane 63 (wave boundary) and the last stored chunk can't get their
        // neighbor via shuffle -> one patch load (in bounds: 4*(mc+1)+3 <=
        // GRID_ELEMS-1 for mc <= NCHUNKM-1).
        float4v nb = a;
        const bool patch = (lane == 63) || (mc == NCHUNKM - 1);
        if (patch) nb = *(const float4v*)(src + 4 * (mc + 1));

        float b0 = __shfl_down(a[0], 1, 64);
        float b1 = __shfl_down(a[1], 1, 64);
        float b2 = __shfl_down(a[2], 1, 64);
        if (patch) { b0 = nb[0]; b1 = nb[1]; b2 = nb[2]; }

        if (m < NCHUNKM) {
            float4v v = {a[3], b0, b1, b2};
            __builtin_nontemporal_store(v, (float4v*)(dst + 3 + 4 * m));
        }
    }

    if (blockIdx.x == 0 && threadIdx.x == 0) {   // edge elements
        dst[0] = src[0];
        dst[1] = src[1];
        dst[2] = src[2];
        dst[GRID_ELEMS - 1] = src[GRID_ELEMS - 1];
    }
}

// Kernel C: overwrite slot j with f_grid (26250 elems) + loss partial sum.
__global__ void __launch_bounds__(256)
fgrid_kernel(const float* __restrict__ ws_in,
             float* __restrict__ ws_out,
             const int* __restrict__ jptr,
             float* __restrict__ out_grid) {    // out + 1 + NPTS
    __shared__ float smem[4];
    const int e = blockIdx.x * 256 + threadIdx.x;

    float s[5];
#pragma unroll
    for (int n = 0; n < 5; ++n) s[n] = ws_in[n];
    const int j = *jptr;

    float local = 0.0f;
    if (e < FG) {
        float w4;
        float f = fgrid_eval(s, e, &w4);
        out_grid[j * FG + e] = f;
        local = f * w4;
    }
#pragma unroll
    for (int off = 32; off > 0; off >>= 1) local += __shfl_down(local, off, 64);
    int lane = threadIdx.x & 63, wave = threadIdx.x >> 6;
    if (lane == 0) smem[wave] = local;
    __syncthreads();
    if (threadIdx.x == 0)
        atomicAdd(&ws_out[6], smem[0] + smem[1] + smem[2] + smem[3]);
}

// Kernel D: finalize loss
__global__ void finalize_kernel(const float* __restrict__ ws,
                                float* __restrict__ out) {
    out[0] = ws[6] - 0.5f * ws[5];
}

extern "C" void kernel_launch(void* const* d_in, const int* in_sizes, int n_in,
                              void* d_out, int out_size, void* d_ws, size_t ws_size,
                              hipStream_t stream) {
    const float* x     = (const float*)d_in[0];   // [5,256,256]
    const float* theta = (const float*)d_in[1];   // [1,256,256]
    const float* grid  = (const float*)d_in[2];   // [2000,5,25,7,6,5]
    const int*   jptr  = (const int*)d_in[3];     // scalar

    float* out = (float*)d_out;
    float* ws  = (float*)d_ws;

    hipMemsetAsync(ws, 0, 7 * sizeof(float), stream);

    reduce_kernel<<<NPTS / 256, 256, 0, stream>>>(x, theta, out + 1, ws);

    const int nblk = (NCHUNKM + COPY_TILE - 1) / COPY_TILE;   // 12818
    copy_kernel<<<nblk, COPY_TPB, 0, stream>>>(grid, out + 1 + NPTS);

    fgrid_kernel<<<(FG + 255) / 256, 256, 0, stream>>>(ws, ws, jptr,
                                                       out + 1 + NPTS);

    finalize_kernel<<<1, 1, 0, stream>>>(ws, out);
}